// Round 6
// baseline (1367.028 us; speedup 1.0000x reference)
//
#include <hip/hip_runtime.h>
#include <stdint.h>

#define T_SEQ 2048
#define HIDN  4096
#define NH    32
#define NKV   8
#define DH    128
#define INTER 14336
#define QKV_N 6144   /* (32+16)*128 */
#define EPSR  1e-5f
#define SCALE 0.08838834764831845f  /* 1/sqrt(128) */
#define KVB   64

typedef __bf16 bf16x8 __attribute__((ext_vector_type(8)));
typedef float  f32x4  __attribute__((ext_vector_type(4)));

__device__ __forceinline__ f32x4 mfma16(bf16x8 a, bf16x8 b, f32x4 c) {
  return __builtin_amdgcn_mfma_f32_16x16x32_bf16(a, b, c, 0, 0, 0);
}

__device__ __forceinline__ void glds16(const void* g, void* l) {
  __builtin_amdgcn_global_load_lds(
      (__attribute__((address_space(1))) void*)g,
      (__attribute__((address_space(3))) void*)l,
      16, 0, 0);
}

// ---------------- fp32 -> bf16 convert (weights) ----------------
__global__ __launch_bounds__(256) void cvt_bf16_kernel(
    const float* __restrict__ src, __bf16* __restrict__ dst, long n) {
  long stride = (long)gridDim.x * 256 * 8;
  for (long i = ((long)blockIdx.x * 256 + threadIdx.x) * 8; i < n; i += stride) {
    float4 a = *(const float4*)(src + i);
    float4 b = *(const float4*)(src + i + 4);
    bf16x8 o;
    o[0]=(__bf16)a.x; o[1]=(__bf16)a.y; o[2]=(__bf16)a.z; o[3]=(__bf16)a.w;
    o[4]=(__bf16)b.x; o[5]=(__bf16)b.y; o[6]=(__bf16)b.z; o[7]=(__bf16)b.w;
    *(bf16x8*)(dst + i) = o;
  }
}

// -------- cvt w1+w3 -> column-interleaved W13 (bf16) --------
// GEMM B-row c: tau=c>>8, wn=(c>>7)&1, nt=(c>>4)&7, k16=c&15
// maps to (nt<4 ? w1 : w3) row [tau*128 + wn*64 + (nt&3)*16 + k16]
__global__ __launch_bounds__(256) void cvt_w13_kernel(
    const float* __restrict__ w1, const float* __restrict__ w3,
    __bf16* __restrict__ dst) {
  for (int c = blockIdx.x; c < 2 * INTER; c += gridDim.x) {
    int tau = c >> 8, j2 = c & 255;
    int wn = j2 >> 7, j = j2 & 127, nt = j >> 4, k16 = j & 15;
    const float* src = (nt < 4 ? w1 : w3) +
        (size_t)(tau * 128 + wn * 64 + (nt & 3) * 16 + k16) * HIDN;
    __bf16* d = dst + (size_t)c * HIDN;
    int i = threadIdx.x * 16;
    float4 a = *(const float4*)(src + i);
    float4 b = *(const float4*)(src + i + 4);
    float4 e = *(const float4*)(src + i + 8);
    float4 f = *(const float4*)(src + i + 12);
    bf16x8 o0, o1;
    o0[0]=(__bf16)a.x; o0[1]=(__bf16)a.y; o0[2]=(__bf16)a.z; o0[3]=(__bf16)a.w;
    o0[4]=(__bf16)b.x; o0[5]=(__bf16)b.y; o0[6]=(__bf16)b.z; o0[7]=(__bf16)b.w;
    o1[0]=(__bf16)e.x; o1[1]=(__bf16)e.y; o1[2]=(__bf16)e.z; o1[3]=(__bf16)e.w;
    o1[4]=(__bf16)f.x; o1[5]=(__bf16)f.y; o1[6]=(__bf16)f.z; o1[7]=(__bf16)f.w;
    *(bf16x8*)(d + i) = o0;
    *(bf16x8*)(d + i + 8) = o1;
  }
}

// ---------------- RMSNorm: fp32 in -> bf16 out ----------------
__global__ __launch_bounds__(256) void rmsnorm_kernel(
    const float* __restrict__ x, const float* __restrict__ w,
    __bf16* __restrict__ y) {
  const int row = blockIdx.x, tid = threadIdx.x;
  const float* xr = x + (size_t)row * HIDN + tid * 16;
  float4 v0 = ((const float4*)xr)[0];
  float4 v1 = ((const float4*)xr)[1];
  float4 v2 = ((const float4*)xr)[2];
  float4 v3 = ((const float4*)xr)[3];
  float ss = v0.x*v0.x + v0.y*v0.y + v0.z*v0.z + v0.w*v0.w
           + v1.x*v1.x + v1.y*v1.y + v1.z*v1.z + v1.w*v1.w
           + v2.x*v2.x + v2.y*v2.y + v2.z*v2.z + v2.w*v2.w
           + v3.x*v3.x + v3.y*v3.y + v3.z*v3.z + v3.w*v3.w;
  #pragma unroll
  for (int off = 32; off >= 1; off >>= 1) ss += __shfl_xor(ss, off, 64);
  __shared__ float red[4];
  if ((tid & 63) == 0) red[tid >> 6] = ss;
  __syncthreads();
  float rn = rsqrtf((red[0] + red[1] + red[2] + red[3]) * (1.0f / HIDN) + EPSR);
  const float* wr = w + tid * 16;
  #pragma unroll
  for (int h = 0; h < 2; h++) {
    float4 a = ((const float4*)xr)[h*2], b = ((const float4*)xr)[h*2+1];
    float4 wa = ((const float4*)wr)[h*2], wb = ((const float4*)wr)[h*2+1];
    bf16x8 o;
    o[0]=(__bf16)(a.x*rn*wa.x); o[1]=(__bf16)(a.y*rn*wa.y);
    o[2]=(__bf16)(a.z*rn*wa.z); o[3]=(__bf16)(a.w*rn*wa.w);
    o[4]=(__bf16)(b.x*rn*wb.x); o[5]=(__bf16)(b.y*rn*wb.y);
    o[6]=(__bf16)(b.z*rn*wb.z); o[7]=(__bf16)(b.w*rn*wb.w);
    *(bf16x8*)(y + (size_t)row * HIDN + tid * 16 + h * 8) = o;
  }
}

// ---- fused: h = p0+p1+resid (f32 out) ; xn = rmsnorm(h)*w (bf16 out) ----
__global__ __launch_bounds__(256) void add3_rms_kernel(
    const float* __restrict__ p, const float* __restrict__ resid,
    const float* __restrict__ w, float* __restrict__ hout,
    __bf16* __restrict__ xn) {
  const int row = blockIdx.x, tid = threadIdx.x;
  const size_t base = (size_t)row * HIDN + tid * 16;
  const size_t half = (size_t)T_SEQ * HIDN;
  float h[16];
  float ss = 0.f;
  #pragma unroll
  for (int q = 0; q < 4; q++) {
    float4 a = *(const float4*)(p + base + q * 4);
    float4 b = *(const float4*)(p + half + base + q * 4);
    float4 c = *(const float4*)(resid + base + q * 4);
    h[q*4+0] = a.x + b.x + c.x; h[q*4+1] = a.y + b.y + c.y;
    h[q*4+2] = a.z + b.z + c.z; h[q*4+3] = a.w + b.w + c.w;
    ss += h[q*4]*h[q*4] + h[q*4+1]*h[q*4+1] + h[q*4+2]*h[q*4+2] + h[q*4+3]*h[q*4+3];
    *(float4*)(hout + base + q * 4) = *(float4*)&h[q*4];
  }
  #pragma unroll
  for (int off = 32; off >= 1; off >>= 1) ss += __shfl_xor(ss, off, 64);
  __shared__ float red[4];
  if ((tid & 63) == 0) red[tid >> 6] = ss;
  __syncthreads();
  float rn = rsqrtf((red[0] + red[1] + red[2] + red[3]) * (1.0f / HIDN) + EPSR);
  #pragma unroll
  for (int hb = 0; hb < 2; hb++) {
    bf16x8 o;
    #pragma unroll
    for (int e = 0; e < 8; e++) {
      float wv = w[tid * 16 + hb * 8 + e];
      o[e] = (__bf16)(h[hb*8+e] * rn * wv);
    }
    *(bf16x8*)(xn + base + hb * 8) = o;
  }
}

// ============ 128x256 GEMM, 2 blocks/CU: C = A[M,K] * B[N,K]^T (bf16) ============
// 256 thr / 4 waves (2Mx2N), wave tile 64x128, BK=32, 3-deep circular LDS
// (3 x 24KB = 72KB -> 2 blocks/CU for cross-block MFMA/LDS overlap).
// One s_barrier per K-tile; steady-state vmcnt(6); stage issued AFTER barrier+reads
// (3-deep race-free: buffer being written was lgkm-drained by all waves pre-barrier).
// EPI: 0 = f32 partial at Cout + z*M*N; 1 = bf16; 2 = silu(u)*v interleaved (W13)
template<int EPI>
__global__ __launch_bounds__(256, 2) void gemm128_kernel(
    const __bf16* __restrict__ A, const __bf16* __restrict__ B,
    void* __restrict__ Cout, int M, int N, int Kfull, int KZ, int Nout) {
  extern __shared__ __align__(16) char smem[];
  const int tid = threadIdx.x;
  const int lane = tid & 63;
  const int wv = tid >> 6;        // 0..3
  const int wm = wv >> 1;         // 0..1
  const int wn = wv & 1;          // 0..1
  const int lr = lane & 15, ql = lane >> 4;

  const int gx = gridDim.x, gy = gridDim.y;
  const int nwg = gx * gy;                 // %8==0 for all our shapes
  const int orig = blockIdx.y * gx + blockIdx.x;
  const int cpx = nwg >> 3;
  const int swz = (orig & 7) * cpx + (orig >> 3);
  const int by = swz % gy, bx = swz / gy;
  const int m0 = by * 128, n0 = bx * 256;
  const int kbase = blockIdx.z * KZ;
  const int NT = KZ >> 5;                  // BK=32 tiles

  // staging: 6 x 16B units per thread (A: 2, B: 4); linear LDS dest,
  // inverse-slot-swizzled global source (slot s stored at pos s^((row>>1)&3))
  const char* gS[6]; int lD[6];
  #pragma unroll
  for (int j = 0; j < 6; j++) {
    int u = (j < 2) ? (j * 256 + tid) : (512 + (j - 2) * 256 + tid);
    if (j < 2) {
      int row = u >> 2;
      int s = (u & 3) ^ ((row >> 1) & 3);
      gS[j] = (const char*)(A + (size_t)(m0 + row) * Kfull + kbase) + s * 16;
      lD[j] = u * 16;
    } else {
      int u2 = u - 512;
      int row = u2 >> 2;
      int s = (u2 & 3) ^ ((row >> 1) & 3);
      gS[j] = (const char*)(B + (size_t)(n0 + row) * Kfull + kbase) + s * 16;
      lD[j] = 8192 + u2 * 16;
    }
  }

  // fragment offsets (relative to buffer base)
  const int sA = ql ^ ((lr >> 1) & 3);
  int aoff[4], boff[8];
  #pragma unroll
  for (int mt = 0; mt < 4; mt++) aoff[mt] = (wm * 64 + mt * 16 + lr) * 64 + sA * 16;
  #pragma unroll
  for (int nt = 0; nt < 8; nt++) boff[nt] = 8192 + (wn * 128 + nt * 16 + lr) * 64 + sA * 16;

#define STAGE(t, b) do {                                           \
    const size_t _o = (size_t)(t) * 64;                            \
    char* _d = smem + (b) * 24576;                                 \
    glds16(gS[0] + _o, _d + lD[0]); glds16(gS[1] + _o, _d + lD[1]);\
    glds16(gS[2] + _o, _d + lD[2]); glds16(gS[3] + _o, _d + lD[3]);\
    glds16(gS[4] + _o, _d + lD[4]); glds16(gS[5] + _o, _d + lD[5]);\
  } while (0)
#define LOADFRAGS(b) do {                                          \
    const char* _p = smem + (b) * 24576;                           \
    _Pragma("unroll") for (int _m = 0; _m < 4; _m++)               \
      af[_m] = *(const bf16x8*)(_p + aoff[_m]);                    \
    _Pragma("unroll") for (int _n = 0; _n < 8; _n++)               \
      bf[_n] = *(const bf16x8*)(_p + boff[_n]);                    \
  } while (0)
#define WAITK() do { asm volatile("s_waitcnt lgkmcnt(0)" ::: "memory"); \
    __builtin_amdgcn_sched_barrier(0); } while (0)
#define MFMA32() do {                                              \
    __builtin_amdgcn_s_setprio(1);                                 \
    _Pragma("unroll") for (int _m = 0; _m < 4; _m++)               \
      _Pragma("unroll") for (int _n = 0; _n < 8; _n++)             \
        acc[_m][_n] = mfma16(af[_m], bf[_n], acc[_m][_n]);         \
    __builtin_amdgcn_s_setprio(0);                                 \
  } while (0)
#define INC3(v) v = (v == 2) ? 0 : v + 1

  f32x4 acc[4][8] = {};
  bf16x8 af[4], bf[8];

  STAGE(0, 0); STAGE(1, 1);
  int bufi = 0, sbufi = 2;
  for (int t = 0; t < NT - 2; ++t) {
    asm volatile("s_waitcnt vmcnt(6)" ::: "memory");
    __builtin_amdgcn_s_barrier();
    LOADFRAGS(bufi);
    STAGE(t + 2, sbufi);
    WAITK(); MFMA32();
    INC3(bufi); INC3(sbufi);
  }
  asm volatile("s_waitcnt vmcnt(6)" ::: "memory");
  __builtin_amdgcn_s_barrier();
  LOADFRAGS(bufi);
  WAITK(); MFMA32();
  INC3(bufi);
  asm volatile("s_waitcnt vmcnt(0)" ::: "memory");
  __builtin_amdgcn_s_barrier();
  LOADFRAGS(bufi);
  WAITK(); MFMA32();

#undef STAGE
#undef LOADFRAGS
#undef WAITK
#undef MFMA32
#undef INC3

  // epilogue
  #pragma unroll
  for (int mt = 0; mt < 4; mt++) {
    #pragma unroll
    for (int r = 0; r < 4; r++) {
      int rr = m0 + wm * 64 + mt * 16 + ql * 4 + r;
      if (EPI == 2) {
        // u = acc[mt][nt], v = acc[mt][nt+4]; out col = n0/2 + wn*64 + nt*16 + lr
        #pragma unroll
        for (int nt = 0; nt < 4; nt++) {
          float u = acc[mt][nt][r];
          float v = acc[mt][nt + 4][r];
          float g = u / (1.0f + __expf(-u)) * v;
          int cc = (n0 >> 1) + wn * 64 + nt * 16 + lr;
          ((__bf16*)Cout)[(size_t)rr * Nout + cc] = (__bf16)g;
        }
      } else {
        #pragma unroll
        for (int nt = 0; nt < 8; nt++) {
          int cc = n0 + wn * 128 + nt * 16 + lr;
          size_t ix = (size_t)rr * N + cc;
          float val = acc[mt][nt][r];
          if (EPI == 0) ((float*)Cout)[(size_t)blockIdx.z * M * N + ix] = val;
          else          ((__bf16*)Cout)[ix] = (__bf16)val;
        }
      }
    }
  }
}

// ---------------- split-K combine: out = p[0] + p[1] + resid ----------------
__global__ __launch_bounds__(256) void add3_kernel(
    const float* __restrict__ p, const float* __restrict__ r,
    float* __restrict__ o, long n) {
  long stride = (long)gridDim.x * 1024;
  for (long i = ((long)blockIdx.x * 256 + threadIdx.x) * 4; i < n; i += stride) {
    float4 a = *(const float4*)(p + i);
    float4 b = *(const float4*)(p + n + i);
    float4 c = *(const float4*)(r + i);
    float4 o4;
    o4.x = a.x + b.x + c.x; o4.y = a.y + b.y + c.y;
    o4.z = a.z + b.z + c.z; o4.w = a.w + b.w + c.w;
    *(float4*)(o + i) = o4;
  }
}

// ---------------- RoPE: qkv(bf16) -> q_r, k_r (bf16) ----------------
__global__ __launch_bounds__(256) void rope_kernel(
    const __bf16* __restrict__ qkv, __bf16* __restrict__ q_r,
    __bf16* __restrict__ k_r) {
  const int t = blockIdx.x, tid = threadIdx.x;
  __shared__ float cs[64], sn[64];
  if (tid < 64) {
    float inv = exp2f(-(float)tid * (19.931568569324174f / 64.0f)); // theta=1e6
    float f = (float)t * inv;
    cs[tid] = cosf(f);
    sn[tid] = sinf(f);
  }
  __syncthreads();
  const __bf16* row = qkv + (size_t)t * QKV_N;
  for (int it = tid; it < 40 * 64; it += 256) {
    int hh = it >> 6, i = it & 63;
    float x1 = (float)row[hh * 128 + i];
    float x2 = (float)row[hh * 128 + 64 + i];
    float c = cs[i], s = sn[i];
    float o1 = x1 * c - x2 * s;
    float o2 = x2 * c + x1 * s;
    if (hh < NH) {
      __bf16* qo = q_r + (size_t)t * HIDN + hh * 128;
      qo[i] = (__bf16)o1;
      qo[64 + i] = (__bf16)o2;
    } else {
      __bf16* ko = k_r + (size_t)t * (NKV * DH) + (hh - NH) * 128;
      ko[i] = (__bf16)o1;
      ko[64 + i] = (__bf16)o2;
    }
  }
}

// ---------------- V transpose: qkv -> v_t[kh][d][t] ----------------
__global__ __launch_bounds__(256) void vtrans_kernel(
    const __bf16* __restrict__ qkv, __bf16* __restrict__ v_t) {
  __shared__ __bf16 tile[64][136];
  const int tid = threadIdx.x;
  const int t0 = blockIdx.x * 64, kh = blockIdx.y;
  #pragma unroll
  for (int i = 0; i < 4; i++) {
    int u = i * 256 + tid;
    int row = u >> 4, c = (u & 15) * 8;
    *(bf16x8*)&tile[row][c] =
        *(const bf16x8*)(qkv + (size_t)(t0 + row) * QKV_N + (NH + NKV) * DH + kh * DH + c);
  }
  __syncthreads();
  const int d = tid & 127, th = (tid >> 7) * 32;
  #pragma unroll
  for (int j = 0; j < 4; j++) {
    int t = th + j * 8;
    bf16x8 o;
    #pragma unroll
    for (int e = 0; e < 8; e++) o[e] = tile[t + e][d];
    *(bf16x8*)(v_t + ((size_t)kh * DH + d) * T_SEQ + t0 + t) = o;
  }
}

// ---------------- Flash attention v2 (causal, GQA, KVB=64) ----------------
__global__ __launch_bounds__(256) void attn_kernel(
    const __bf16* __restrict__ q_r, const __bf16* __restrict__ k_r,
    const __bf16* __restrict__ v_t, __bf16* __restrict__ attn_o) {
  __shared__ __align__(16) __bf16 Ks[KVB * 128];    // 16KB
  __shared__ __align__(16) __bf16 Vs[128 * KVB];    // 16KB, rows = d
  __shared__ __align__(16) __bf16 Pl[4 * 16 * KVB]; // 8KB

  const int tid = threadIdx.x;
  const int lane = tid & 63, wv = tid >> 6;
  const int lr = lane & 15, g = lane >> 4;
  const int qt = gridDim.x - 1 - blockIdx.x;   // heavy blocks first
  const int h = blockIdx.y;
  const int kh = h >> 2;  // G = 4
  const int q0b = qt * 64;
  const int q0w = q0b + wv * 16;

  bf16x8 qf[4];
  {
    const __bf16* qp = q_r + (size_t)(q0w + lr) * HIDN + h * DH + g * 8;
    #pragma unroll
    for (int kk = 0; kk < 4; kk++) qf[kk] = *(const bf16x8*)(qp + kk * 32);
  }

  f32x4 o[8] = {};
  float mrun[4] = {-1e30f, -1e30f, -1e30f, -1e30f};
  float lrun[4] = {0.f, 0.f, 0.f, 0.f};
  char* PlW = (char*)Pl + wv * 2048;

  for (int kv0 = 0; kv0 < q0b + KVB; kv0 += KVB) {
    __syncthreads();
    // stage K [64][128] via glds16, xor swizzle (row&7)<<4
    #pragma unroll
    for (int i = 0; i < 4; i++) {
      int u = i * 256 + tid;
      int row = u >> 4;
      int cb = ((u & 15) * 16) ^ ((row & 7) << 4);
      glds16((const char*)(k_r + (size_t)(kv0 + row) * (NKV * DH) + kh * DH) + cb,
             (char*)Ks + u * 16);
    }
    // stage Vt [128 d][64 t] via glds16, xor swizzle
    #pragma unroll
    for (int i = 0; i < 4; i++) {
      int u = i * 256 + tid;
      int row = u >> 3;
      int cb = ((u & 7) * 16) ^ ((row & 7) << 4);
      glds16((const char*)(v_t + ((size_t)kh * DH + row) * T_SEQ + kv0) + cb,
             (char*)Vs + u * 16);
    }
    __syncthreads();

    if (q0w + 15 >= kv0) {
      f32x4 s[4] = {};
      #pragma unroll
      for (int kk = 0; kk < 4; kk++) {
        #pragma unroll
        for (int jt = 0; jt < 4; jt++) {
          int krow = jt * 16 + lr;
          int cb = (kk * 64 + g * 16) ^ ((krow & 7) << 4);
          bf16x8 kf = *(const bf16x8*)((char*)Ks + krow * 256 + cb);
          s[jt] = mfma16(qf[kk], kf, s[jt]);
        }
      }
      const bool need_mask = (kv0 + KVB - 1) > q0w;
      #pragma unroll
      for (int r = 0; r < 4; r++) {
        int qpos = q0w + g * 4 + r;
        int prow = g * 4 + r;
        float p[4];
        #pragma unroll
        for (int jt = 0; jt < 4; jt++) {
          float v = s[jt][r] * SCALE;
          if (need_mask && (kv0 + jt * 16 + lr > qpos)) v = -1e30f;
          p[jt] = v;
        }
        float mx = fmaxf(fmaxf(p[0], p[1]), fmaxf(p[2], p[3]));
        #pragma unroll
        for (int off = 1; off < 16; off <<= 1) mx = fmaxf(mx, __shfl_xor(mx, off, 64));
        float mn = fmaxf(mrun[r], mx);
        float corr = __expf(mrun[r] - mn);
        mrun[r] = mn;
        float ps = 0.f;
        #pragma unroll
        for (int jt = 0; jt < 4; jt++) {
          p[jt] = __expf(p[jt] - mn);
          ps += p[jt];
          int cbyte = ((jt * 16 + lr) * 2) ^ ((prow & 7) << 4);
          *(__bf16*)(PlW + prow * 128 + cbyte) = (__bf16)p[jt];
        }
        #pragma unroll
        for (int off = 1; off < 16; off <<= 1) ps += __shfl_xor(ps, off, 64);
        lrun[r] = lrun[r] * corr + ps;
        #pragma unroll
        for (int nt = 0; nt < 8; nt++) o[nt][r] *= corr;
      }
      // PV
      bf16x8 pa[2];
      #pragma unroll
      for (int ks = 0; ks < 2; ks++)
        pa[ks] = *(const bf16x8*)(PlW + lr * 128 + ((g * 16 + ks * 64) ^ ((lr & 7) << 4)));
      #pragma unroll
      for (int nt = 0; nt < 8; nt++) {
        #pragma unroll
        for (int ks = 0; ks < 2; ks++) {
          int vrow = nt * 16 + lr;
          int cb = (ks * 64 + g * 16) ^ ((vrow & 7) << 4);
          bf16x8 vf = *(const bf16x8*)((char*)Vs + vrow * 128 + cb);
          o[nt] = mfma16(pa[ks], vf, o[nt]);
        }
      }
    }
  }

  #pragma unroll
  for (int nt = 0; nt < 8; nt++) {
    #pragma unroll
    for (int r = 0; r < 4; r++) {
      int qrow = q0w + g * 4 + r;
      int d = nt * 16 + lr;
      attn_o[(size_t)qrow * HIDN + h * DH + d] = (__bf16)(o[nt][r] / lrun[r]);
    }
  }
}

extern "C" void kernel_launch(void* const* d_in, const int* in_sizes, int n_in,
                              void* d_out, int out_size, void* d_ws, size_t ws_size,
                              hipStream_t stream) {
  const float* hidden = (const float*)d_in[0];
  const float* wqkv = (const float*)d_in[2];
  const float* wo   = (const float*)d_in[3];
  const float* w1   = (const float*)d_in[4];
  const float* w3   = (const float*)d_in[5];
  const float* w2   = (const float*)d_in[6];
  const float* anw  = (const float*)d_in[7];
  const float* fnw  = (const float*)d_in[8];

  char* ws = (char*)d_ws;
  const size_t SZ_XN   = (size_t)T_SEQ * HIDN * 2;      // 16,777,216
  const size_t SZ_QKV  = (size_t)T_SEQ * QKV_N * 2;     // 25,165,824
  const size_t SZ_KR   = (size_t)T_SEQ * NKV * DH * 2;  //  4,194,304
  const size_t SZ_H    = (size_t)T_SEQ * HIDN * 4;      // 33,554,432
  const size_t SZ_UV   = (size_t)T_SEQ * INTER * 2;     // 58,720,256

  const size_t W_QKV = (size_t)QKV_N * HIDN * 2;   // 50,331,648
  const size_t W_O   = (size_t)HIDN * HIDN * 2;    // 33,554,432
  const size_t W_I   = (size_t)INTER * HIDN * 2;   // 117,440,512
  const size_t W_TOTAL = W_QKV + W_O + 3 * W_I;    // 436,207,616

  char* act = ws + W_TOTAL;

  __bf16* xn1    = (__bf16*)(act);
  __bf16* qkv    = (__bf16*)(act + SZ_XN);
  __bf16* q_r    = (__bf16*)(act + SZ_XN + SZ_QKV);
  __bf16* gbuf   = (__bf16*)(act);                      // W13 output overlays xn1|qkv|q_r
  __bf16* k_r    = (__bf16*)(act + SZ_UV);
  __bf16* attn_o = (__bf16*)(act + SZ_UV + SZ_KR);
  float*  hbuf   = (float*) (act + SZ_UV + SZ_KR + SZ_XN);
  __bf16* v_t    = (__bf16*)(act + SZ_UV + SZ_KR + SZ_XN);  // overlays hbuf (dead until O-proj)
  __bf16* xn2    = (__bf16*)(act + SZ_UV + SZ_KR + SZ_XN + SZ_H);
  float*  pbuf   = (float*)(act + SZ_UV + SZ_KR + SZ_XN + SZ_H + SZ_XN);  // split-K partials

  __bf16* wqkv_b = (__bf16*)(ws);
  __bf16* wo_b   = (__bf16*)(ws + W_QKV);
  __bf16* w13_b  = (__bf16*)(ws + W_QKV + W_O);            // interleaved, 2*W_I
  __bf16* w2_b   = (__bf16*)(ws + W_QKV + W_O + 2 * W_I);

  const int LDS_BYTES = 73728;
  hipFuncSetAttribute((const void*)gemm128_kernel<0>,
                      hipFuncAttributeMaxDynamicSharedMemorySize, LDS_BYTES);
  hipFuncSetAttribute((const void*)gemm128_kernel<1>,
                      hipFuncAttributeMaxDynamicSharedMemorySize, LDS_BYTES);
  hipFuncSetAttribute((const void*)gemm128_kernel<2>,
                      hipFuncAttributeMaxDynamicSharedMemorySize, LDS_BYTES);

  cvt_bf16_kernel<<<2048, 256, 0, stream>>>(wqkv, wqkv_b, (long)QKV_N * HIDN);
  cvt_bf16_kernel<<<2048, 256, 0, stream>>>(wo,   wo_b,   (long)HIDN * HIDN);
  cvt_w13_kernel<<<2048, 256, 0, stream>>>(w1, w3, w13_b);
  cvt_bf16_kernel<<<2048, 256, 0, stream>>>(w2,   w2_b,   (long)HIDN * INTER);

  rmsnorm_kernel<<<T_SEQ, 256, 0, stream>>>(hidden, anw, xn1);
  // QKV: M=2048 N=6144 K=4096 -> grid 24x16 = 384 blocks
  gemm128_kernel<1><<<dim3(QKV_N / 256, T_SEQ / 128, 1), 256, LDS_BYTES, stream>>>(
      xn1, wqkv_b, qkv, T_SEQ, QKV_N, HIDN, HIDN, QKV_N);
  rope_kernel<<<T_SEQ, 256, 0, stream>>>(qkv, q_r, k_r);
  vtrans_kernel<<<dim3(T_SEQ / 64, NKV), 256, 0, stream>>>(qkv, v_t);
  attn_kernel<<<dim3(T_SEQ / 64, NH), 256, 0, stream>>>(q_r, k_r, v_t, attn_o);
  // O-proj: split-K=2 -> 16x16x2 = 512 blocks (full 2-round occupancy)
  gemm128_kernel<0><<<dim3(HIDN / 256, T_SEQ / 128, 2), 256, LDS_BYTES, stream>>>(
      attn_o, wo_b, pbuf, T_SEQ, HIDN, HIDN, HIDN / 2, HIDN);
  add3_rms_kernel<<<T_SEQ, 256, 0, stream>>>(pbuf, hidden, fnw, hbuf, xn2);
  // W13 fused (u|v interleaved) + silu epilogue: N=28672 -> 112x16 = 1792 blocks
  gemm128_kernel<2><<<dim3(2 * INTER / 256, T_SEQ / 128, 1), 256, LDS_BYTES, stream>>>(
      xn2, w13_b, gbuf, T_SEQ, 2 * INTER, HIDN, HIDN, INTER);
  // W2: split-K=2 -> 512 blocks
  gemm128_kernel<0><<<dim3(HIDN / 256, T_SEQ / 128, 2), 256, LDS_BYTES, stream>>>(
      gbuf, w2_b, pbuf, T_SEQ, HIDN, INTER, INTER / 2, HIDN);
  add3_kernel<<<2048, 256, 0, stream>>>(pbuf, hbuf, (float*)d_out, (long)T_SEQ * HIDN);
}